// Round 1
// baseline (1668.068 us; speedup 1.0000x reference)
//
#include <hip/hip_runtime.h>
#include <hip/hip_bf16.h>

#define N_NODES 50000
#define N_EDGES 800000
#define N_GRAPHS 64
#define IN_DIM 128
#define HID_DIM 256
#define POOL_CHUNKS 16

// ---------------- degree / normalization ----------------

__global__ void k_deg_init(float* __restrict__ deg) {
    int i = blockIdx.x * blockDim.x + threadIdx.x;
    if (i < N_NODES) deg[i] = 1.0f;  // self-loop
}

__global__ void k_deg_count(const int* __restrict__ dst, float* __restrict__ deg) {
    int e = blockIdx.x * blockDim.x + threadIdx.x;
    if (e < N_EDGES) atomicAdd(&deg[dst[e]], 1.0f);
}

__global__ void k_dinv(float* __restrict__ deg) {
    int i = blockIdx.x * blockDim.x + threadIdx.x;
    if (i < N_NODES) deg[i] = rsqrtf(deg[i]);   // deg >= 1 always
}

// ---------------- fp32 tiled GEMM: C[M,N] = A[M,K] @ B[K,N] ----------------
// 64x64 tile, BK=16, 256 threads, 4x4 micro-tile per thread.

#define TILE 64
#define BK 16

__global__ __launch_bounds__(256)
void k_gemm(const float* __restrict__ A, const float* __restrict__ B,
            float* __restrict__ C, int M, int N, int K) {
    __shared__ float As[BK][TILE + 1];  // As[k][m] (transposed), +1 pad
    __shared__ float Bs[BK][TILE + 1];  // Bs[k][n], +1 pad

    const int tid = threadIdx.x;
    const int tx = tid & 15;        // col group
    const int ty = tid >> 4;        // row group
    const int m0 = blockIdx.x * TILE;
    const int n0 = blockIdx.y * TILE;

    float acc[4][4] = {};

    for (int k0 = 0; k0 < K; k0 += BK) {
        // load A tile: thread -> row = tid>>2 (0..63), k = (tid&3)*4 (+0..3)
        {
            int row = tid >> 2;
            int kk  = (tid & 3) * 4;
            int gm  = m0 + row;
            float4 v = make_float4(0.f, 0.f, 0.f, 0.f);
            if (gm < M)
                v = *reinterpret_cast<const float4*>(&A[(size_t)gm * K + k0 + kk]);
            As[kk + 0][row] = v.x;
            As[kk + 1][row] = v.y;
            As[kk + 2][row] = v.z;
            As[kk + 3][row] = v.w;
        }
        // load B tile: thread -> krow = tid>>4 (0..15), n = (tid&15)*4 (+0..3)
        {
            int krow = tid >> 4;
            int nn   = (tid & 15) * 4;
            float4 v = *reinterpret_cast<const float4*>(&B[(size_t)(k0 + krow) * N + n0 + nn]);
            Bs[krow][nn + 0] = v.x;
            Bs[krow][nn + 1] = v.y;
            Bs[krow][nn + 2] = v.z;
            Bs[krow][nn + 3] = v.w;
        }
        __syncthreads();

        #pragma unroll
        for (int kk = 0; kk < BK; ++kk) {
            float a[4], b[4];
            #pragma unroll
            for (int i = 0; i < 4; ++i) a[i] = As[kk][ty * 4 + i];
            #pragma unroll
            for (int j = 0; j < 4; ++j) b[j] = Bs[kk][tx * 4 + j];
            #pragma unroll
            for (int i = 0; i < 4; ++i)
                #pragma unroll
                for (int j = 0; j < 4; ++j)
                    acc[i][j] += a[i] * b[j];
        }
        __syncthreads();
    }

    #pragma unroll
    for (int i = 0; i < 4; ++i) {
        int gm = m0 + ty * 4 + i;
        if (gm < M) {
            #pragma unroll
            for (int j = 0; j < 4; ++j)
                C[(size_t)gm * N + n0 + tx * 4 + j] = acc[i][j];
        }
    }
}

// ---------------- aggregation ----------------
// out[n][c] = b[c] + lin[n][c] * dinv[n]^2   (bias + self-loop message)

__global__ void k_agg_init(const float* __restrict__ lin, const float* __restrict__ dinv,
                           const float* __restrict__ bias, float* __restrict__ out) {
    int n = blockIdx.x;
    int c = threadIdx.x;
    float di = dinv[n];
    out[(size_t)n * HID_DIM + c] = bias[c] + lin[(size_t)n * HID_DIM + c] * di * di;
}

// out[dst][c] += lin[src][c] * dinv[src]*dinv[dst]
__global__ void k_agg_edges(const int* __restrict__ src, const int* __restrict__ dst,
                            const float* __restrict__ lin, const float* __restrict__ dinv,
                            float* __restrict__ out) {
    int c = threadIdx.x;
    for (int e = blockIdx.x; e < N_EDGES; e += gridDim.x) {
        int s = src[e];
        int d = dst[e];
        float norm = dinv[s] * dinv[d];
        atomicAdd(&out[(size_t)d * HID_DIM + c], lin[(size_t)s * HID_DIM + c] * norm);
    }
}

__global__ void k_relu(float* __restrict__ h, size_t n) {
    size_t i = (size_t)blockIdx.x * blockDim.x + threadIdx.x;
    if (i < n) h[i] = fmaxf(h[i], 0.0f);
}

// ---------------- pooling + FC ----------------

// bounds[g] = first index i with batch[i] >= g (batch sorted). g in [0, N_GRAPHS].
__global__ void k_bounds(const int* __restrict__ batch, int* __restrict__ bounds) {
    int g = blockIdx.x * blockDim.x + threadIdx.x;
    if (g > N_GRAPHS) return;
    int lo = 0, hi = N_NODES;
    while (lo < hi) {
        int mid = (lo + hi) >> 1;
        if (batch[mid] < g) lo = mid + 1; else hi = mid;
    }
    bounds[g] = lo;
}

__global__ void k_sums_init(float* __restrict__ sums) {
    int i = blockIdx.x * blockDim.x + threadIdx.x;
    if (i < N_GRAPHS * HID_DIM) sums[i] = 0.0f;
}

__global__ void k_pool(const float* __restrict__ h, const int* __restrict__ bounds,
                       float* __restrict__ sums) {
    int g = blockIdx.x / POOL_CHUNKS;
    int chunk = blockIdx.x % POOL_CHUNKS;
    int c = threadIdx.x;
    int s = bounds[g], e = bounds[g + 1];
    int len = e - s;
    if (len <= 0) return;
    int per = (len + POOL_CHUNKS - 1) / POOL_CHUNKS;
    int ns = s + chunk * per;
    int ne = min(ns + per, e);
    if (ns >= ne) return;
    float sum = 0.0f;
    for (int n = ns; n < ne; ++n) sum += h[(size_t)n * HID_DIM + c];
    atomicAdd(&sums[g * HID_DIM + c], sum);
}

// out[g] = (sums[g] / max(cnt,1)) . Wfc + bfc
__global__ void k_final(const float* __restrict__ sums, const int* __restrict__ bounds,
                        const float* __restrict__ Wfc, const float* __restrict__ bfc,
                        float* __restrict__ out) {
    __shared__ float red[HID_DIM];
    int g = blockIdx.x;
    int c = threadIdx.x;
    float cnt = (float)(bounds[g + 1] - bounds[g]);
    float v = sums[g * HID_DIM + c] / fmaxf(cnt, 1.0f) * Wfc[c];
    red[c] = v;
    __syncthreads();
    for (int s = HID_DIM / 2; s > 0; s >>= 1) {
        if (c < s) red[c] += red[c + s];
        __syncthreads();
    }
    if (c == 0) out[g] = red[0] + bfc[0];
}

// ---------------- launch ----------------

extern "C" void kernel_launch(void* const* d_in, const int* in_sizes, int n_in,
                              void* d_out, int out_size, void* d_ws, size_t ws_size,
                              hipStream_t stream) {
    const float* x    = (const float*)d_in[0];
    const int*   ei   = (const int*)d_in[1];      // [2, E] flat
    const int*   batch= (const int*)d_in[2];
    const float* W1   = (const float*)d_in[3];
    const float* b1   = (const float*)d_in[4];
    const float* W2   = (const float*)d_in[5];
    const float* b2   = (const float*)d_in[6];
    const float* Wfc  = (const float*)d_in[7];
    const float* bfc  = (const float*)d_in[8];
    float* out = (float*)d_out;

    const int* src = ei;
    const int* dst = ei + N_EDGES;

    // workspace layout
    char* ws = (char*)d_ws;
    const size_t BUF_BYTES = (size_t)N_NODES * HID_DIM * sizeof(float);  // 51.2 MB
    float* bufA   = (float*)(ws);                               // lin outputs
    float* bufB   = (float*)(ws + BUF_BYTES);                   // agg outputs
    float* dinv   = (float*)(ws + 2 * BUF_BYTES);               // 200 KB (deg then dinv)
    float* sums   = (float*)(ws + 2 * BUF_BYTES + 204800);      // 64*256 f32
    int*   bounds = (int*)  (ws + 2 * BUF_BYTES + 204800 + 65536);

    const size_t NH = (size_t)N_NODES * HID_DIM;

    // 1. degrees -> dinv
    k_deg_init<<<(N_NODES + 255) / 256, 256, 0, stream>>>(dinv);
    k_deg_count<<<(N_EDGES + 255) / 256, 256, 0, stream>>>(dst, dinv);
    k_dinv<<<(N_NODES + 255) / 256, 256, 0, stream>>>(dinv);

    // 2. layer 1: lin = x @ W1
    {
        dim3 grid((N_NODES + TILE - 1) / TILE, HID_DIM / TILE);
        k_gemm<<<grid, 256, 0, stream>>>(x, W1, bufA, N_NODES, HID_DIM, IN_DIM);
    }
    // 3. aggregate + bias, relu
    k_agg_init<<<N_NODES, HID_DIM, 0, stream>>>(bufA, dinv, b1, bufB);
    k_agg_edges<<<32768, HID_DIM, 0, stream>>>(src, dst, bufA, dinv, bufB);
    k_relu<<<(int)((NH + 255) / 256), 256, 0, stream>>>(bufB, NH);

    // 4. layer 2: lin = h1 @ W2
    {
        dim3 grid((N_NODES + TILE - 1) / TILE, HID_DIM / TILE);
        k_gemm<<<grid, 256, 0, stream>>>(bufB, W2, bufA, N_NODES, HID_DIM, HID_DIM);
    }
    k_agg_init<<<N_NODES, HID_DIM, 0, stream>>>(bufA, dinv, b2, bufB);
    k_agg_edges<<<32768, HID_DIM, 0, stream>>>(src, dst, bufA, dinv, bufB);
    k_relu<<<(int)((NH + 255) / 256), 256, 0, stream>>>(bufB, NH);

    // 5. pool + fc
    k_bounds<<<1, 128, 0, stream>>>(batch, bounds);
    k_sums_init<<<(N_GRAPHS * HID_DIM + 255) / 256, 256, 0, stream>>>(sums);
    k_pool<<<N_GRAPHS * POOL_CHUNKS, HID_DIM, 0, stream>>>(bufB, bounds, sums);
    k_final<<<N_GRAPHS, HID_DIM, 0, stream>>>(sums, bounds, Wfc, bfc, out);
}

// Round 2
// 643.457 us; speedup vs baseline: 2.5924x; 2.5924x over previous
//
#include <hip/hip_runtime.h>
#include <hip/hip_bf16.h>

#define N_NODES 50000
#define N_EDGES 800000
#define N_GRAPHS 64
#define IN_DIM 128
#define HID_DIM 256
#define POOL_CHUNKS 16

// ---------------- degree / normalization / CSR build ----------------

__global__ void k_deg_count(const int* __restrict__ dst, int* __restrict__ deg) {
    int e = blockIdx.x * blockDim.x + threadIdx.x;
    if (e < N_EDGES) atomicAdd(&deg[dst[e]], 1);
}

__global__ void k_dinv(const int* __restrict__ deg, float* __restrict__ dinv) {
    int i = blockIdx.x * blockDim.x + threadIdx.x;
    if (i < N_NODES) dinv[i] = rsqrtf((float)deg[i] + 1.0f);  // +1 self-loop
}

#define SCAN_THREADS 1024
#define SCAN_CHUNK ((N_NODES + SCAN_THREADS - 1) / SCAN_THREADS)  // 49

__global__ __launch_bounds__(SCAN_THREADS)
void k_scan(const int* __restrict__ deg, int* __restrict__ row_start) {
    __shared__ int part[SCAN_THREADS];
    int t = threadIdx.x;
    int s0 = t * SCAN_CHUNK;
    int s1 = min(s0 + SCAN_CHUNK, N_NODES);
    int sum = 0;
    for (int i = s0; i < s1; ++i) sum += deg[i];
    part[t] = sum;
    __syncthreads();
    // inclusive Hillis-Steele scan over 1024 partials
    for (int off = 1; off < SCAN_THREADS; off <<= 1) {
        int v = (t >= off) ? part[t - off] : 0;
        __syncthreads();
        part[t] += v;
        __syncthreads();
    }
    int base = part[t] - sum;  // exclusive prefix of this chunk
    int run = base;
    for (int i = s0; i < s1; ++i) { row_start[i] = run; run += deg[i]; }
    if (t == SCAN_THREADS - 1) row_start[N_NODES] = run;  // == N_EDGES
}

__global__ void k_csr_fill(const int* __restrict__ src, const int* __restrict__ dst,
                           const int* __restrict__ row_start, int* __restrict__ cursor,
                           int* __restrict__ col) {
    int e = blockIdx.x * blockDim.x + threadIdx.x;
    if (e < N_EDGES) {
        int d = dst[e];
        int pos = atomicAdd(&cursor[d], 1);
        col[row_start[d] + pos] = src[e];
    }
}

// ---------------- fp32 tiled GEMM: C[M,N] = (A[M,K] @ B[K,N]) * dinv[m] ----
// 64x64 tile, BK=16, 256 threads, 4x4 micro-tile per thread.

#define TILE 64
#define BK 16

__global__ __launch_bounds__(256)
void k_gemm(const float* __restrict__ A, const float* __restrict__ B,
            const float* __restrict__ dinv, float* __restrict__ C,
            int M, int N, int K) {
    __shared__ float As[BK][TILE + 1];  // As[k][m] (transposed), +1 pad
    __shared__ float Bs[BK][TILE + 1];  // Bs[k][n], +1 pad

    const int tid = threadIdx.x;
    const int tx = tid & 15;        // col group
    const int ty = tid >> 4;        // row group
    const int m0 = blockIdx.x * TILE;
    const int n0 = blockIdx.y * TILE;

    float acc[4][4] = {};

    for (int k0 = 0; k0 < K; k0 += BK) {
        {
            int row = tid >> 2;
            int kk  = (tid & 3) * 4;
            int gm  = m0 + row;
            float4 v = make_float4(0.f, 0.f, 0.f, 0.f);
            if (gm < M)
                v = *reinterpret_cast<const float4*>(&A[(size_t)gm * K + k0 + kk]);
            As[kk + 0][row] = v.x;
            As[kk + 1][row] = v.y;
            As[kk + 2][row] = v.z;
            As[kk + 3][row] = v.w;
        }
        {
            int krow = tid >> 4;
            int nn   = (tid & 15) * 4;
            float4 v = *reinterpret_cast<const float4*>(&B[(size_t)(k0 + krow) * N + n0 + nn]);
            Bs[krow][nn + 0] = v.x;
            Bs[krow][nn + 1] = v.y;
            Bs[krow][nn + 2] = v.z;
            Bs[krow][nn + 3] = v.w;
        }
        __syncthreads();

        #pragma unroll
        for (int kk = 0; kk < BK; ++kk) {
            float a[4], b[4];
            #pragma unroll
            for (int i = 0; i < 4; ++i) a[i] = As[kk][ty * 4 + i];
            #pragma unroll
            for (int j = 0; j < 4; ++j) b[j] = Bs[kk][tx * 4 + j];
            #pragma unroll
            for (int i = 0; i < 4; ++i)
                #pragma unroll
                for (int j = 0; j < 4; ++j)
                    acc[i][j] += a[i] * b[j];
        }
        __syncthreads();
    }

    #pragma unroll
    for (int i = 0; i < 4; ++i) {
        int gm = m0 + ty * 4 + i;
        if (gm < M) {
            float dm = dinv[gm];
            #pragma unroll
            for (int j = 0; j < 4; ++j)
                C[(size_t)gm * N + n0 + tx * 4 + j] = acc[i][j] * dm;
        }
    }
}

// ---------------- CSR aggregation (one wave per node, float4 per lane) -----
// y is pre-scaled by dinv[src]. out[n] = relu(dinv[n]*(y[n] + sum y[col]) + b)

__global__ __launch_bounds__(256)
void k_agg_csr(const float* __restrict__ y, const int* __restrict__ row_start,
               const int* __restrict__ col, const float* __restrict__ dinv,
               const float* __restrict__ bias, float* __restrict__ out) {
    int wave = threadIdx.x >> 6;           // 0..3
    int lane = threadIdx.x & 63;
    int n = blockIdx.x * 4 + wave;
    if (n >= N_NODES) return;

    const float4* y4 = (const float4*)y;   // 64 float4 per node row
    float4 acc = y4[(size_t)n * 64 + lane];  // self-loop term (y pre-scaled)
    int e0 = row_start[n], e1 = row_start[n + 1];
    for (int e = e0; e < e1; ++e) {
        int s = col[e];                    // wave-uniform -> broadcast load
        float4 v = y4[(size_t)s * 64 + lane];
        acc.x += v.x; acc.y += v.y; acc.z += v.z; acc.w += v.w;
    }
    float dn = dinv[n];
    float4 b = ((const float4*)bias)[lane];
    float4 o;
    o.x = fmaxf(acc.x * dn + b.x, 0.f);
    o.y = fmaxf(acc.y * dn + b.y, 0.f);
    o.z = fmaxf(acc.z * dn + b.z, 0.f);
    o.w = fmaxf(acc.w * dn + b.w, 0.f);
    ((float4*)out)[(size_t)n * 64 + lane] = o;
}

// ---------------- pooling + FC ----------------

__global__ void k_bounds(const int* __restrict__ batch, int* __restrict__ bounds) {
    int g = blockIdx.x * blockDim.x + threadIdx.x;
    if (g > N_GRAPHS) return;
    int lo = 0, hi = N_NODES;
    while (lo < hi) {
        int mid = (lo + hi) >> 1;
        if (batch[mid] < g) lo = mid + 1; else hi = mid;
    }
    bounds[g] = lo;
}

__global__ void k_sums_init(float* __restrict__ sums) {
    int i = blockIdx.x * blockDim.x + threadIdx.x;
    if (i < N_GRAPHS * HID_DIM) sums[i] = 0.0f;
}

__global__ void k_pool(const float* __restrict__ h, const int* __restrict__ bounds,
                       float* __restrict__ sums) {
    int g = blockIdx.x / POOL_CHUNKS;
    int chunk = blockIdx.x % POOL_CHUNKS;
    int c = threadIdx.x;
    int s = bounds[g], e = bounds[g + 1];
    int len = e - s;
    if (len <= 0) return;
    int per = (len + POOL_CHUNKS - 1) / POOL_CHUNKS;
    int ns = s + chunk * per;
    int ne = min(ns + per, e);
    if (ns >= ne) return;
    float sum = 0.0f;
    for (int n = ns; n < ne; ++n) sum += h[(size_t)n * HID_DIM + c];
    atomicAdd(&sums[g * HID_DIM + c], sum);
}

__global__ void k_final(const float* __restrict__ sums, const int* __restrict__ bounds,
                        const float* __restrict__ Wfc, const float* __restrict__ bfc,
                        float* __restrict__ out) {
    __shared__ float red[HID_DIM];
    int g = blockIdx.x;
    int c = threadIdx.x;
    float cnt = (float)(bounds[g + 1] - bounds[g]);
    float v = sums[g * HID_DIM + c] / fmaxf(cnt, 1.0f) * Wfc[c];
    red[c] = v;
    __syncthreads();
    for (int s = HID_DIM / 2; s > 0; s >>= 1) {
        if (c < s) red[c] += red[c + s];
        __syncthreads();
    }
    if (c == 0) out[g] = red[0] + bfc[0];
}

// ---------------- launch ----------------

extern "C" void kernel_launch(void* const* d_in, const int* in_sizes, int n_in,
                              void* d_out, int out_size, void* d_ws, size_t ws_size,
                              hipStream_t stream) {
    const float* x    = (const float*)d_in[0];
    const int*   ei   = (const int*)d_in[1];      // [2, E] flat
    const int*   batch= (const int*)d_in[2];
    const float* W1   = (const float*)d_in[3];
    const float* b1   = (const float*)d_in[4];
    const float* W2   = (const float*)d_in[5];
    const float* b2   = (const float*)d_in[6];
    const float* Wfc  = (const float*)d_in[7];
    const float* bfc  = (const float*)d_in[8];
    float* out = (float*)d_out;

    const int* src = ei;
    const int* dst = ei + N_EDGES;

    // workspace layout
    char* ws = (char*)d_ws;
    const size_t BUF_BYTES = (size_t)N_NODES * HID_DIM * sizeof(float);  // 51.2 MB
    size_t off = 0;
    float* bufA      = (float*)(ws + off); off += BUF_BYTES;       // y (lin*dinv)
    float* bufB      = (float*)(ws + off); off += BUF_BYTES;       // agg outputs
    int*   deg_i     = (int*)  (ws + off); off += 204800;          // in-degree
    int*   cursor    = (int*)  (ws + off); off += 204800;          // fill cursors
    float* dinv      = (float*)(ws + off); off += 204800;
    int*   row_start = (int*)  (ws + off); off += 204800;          // N_NODES+1
    int*   col       = (int*)  (ws + off); off += (size_t)N_EDGES * 4;  // 3.2 MB
    float* sums      = (float*)(ws + off); off += 65536;
    int*   bounds    = (int*)  (ws + off);

    const size_t NH = (size_t)N_NODES * HID_DIM;
    (void)NH; (void)ws_size; (void)in_sizes; (void)n_in; (void)out_size;

    // 1. CSR build + dinv
    hipMemsetAsync(deg_i, 0, 2 * 204800, stream);  // deg_i + cursor
    k_deg_count<<<(N_EDGES + 255) / 256, 256, 0, stream>>>(dst, deg_i);
    k_dinv<<<(N_NODES + 255) / 256, 256, 0, stream>>>(deg_i, dinv);
    k_scan<<<1, SCAN_THREADS, 0, stream>>>(deg_i, row_start);
    k_csr_fill<<<(N_EDGES + 255) / 256, 256, 0, stream>>>(src, dst, row_start, cursor, col);

    // 2. layer 1: y = (x @ W1) * dinv
    {
        dim3 grid((N_NODES + TILE - 1) / TILE, HID_DIM / TILE);
        k_gemm<<<grid, 256, 0, stream>>>(x, W1, dinv, bufA, N_NODES, HID_DIM, IN_DIM);
    }
    // 3. aggregate (self-loop + bias + relu fused)
    k_agg_csr<<<(N_NODES + 3) / 4, 256, 0, stream>>>(bufA, row_start, col, dinv, b1, bufB);

    // 4. layer 2
    {
        dim3 grid((N_NODES + TILE - 1) / TILE, HID_DIM / TILE);
        k_gemm<<<grid, 256, 0, stream>>>(bufB, W2, dinv, bufA, N_NODES, HID_DIM, HID_DIM);
    }
    k_agg_csr<<<(N_NODES + 3) / 4, 256, 0, stream>>>(bufA, row_start, col, dinv, b2, bufB);

    // 5. pool + fc
    k_bounds<<<1, 128, 0, stream>>>(batch, bounds);
    k_sums_init<<<(N_GRAPHS * HID_DIM + 255) / 256, 256, 0, stream>>>(sums);
    k_pool<<<N_GRAPHS * POOL_CHUNKS, HID_DIM, 0, stream>>>(bufB, bounds, sums);
    k_final<<<N_GRAPHS, HID_DIM, 0, stream>>>(sums, bounds, Wfc, bfc, out);
}

// Round 3
// 465.345 us; speedup vs baseline: 3.5846x; 1.3828x over previous
//
#include <hip/hip_runtime.h>
#include <hip/hip_bf16.h>

#define N_NODES 50000
#define N_EDGES 800000
#define N_GRAPHS 64
#define IN_DIM 128
#define HID_DIM 256
#define POOL_CHUNKS 16

typedef short sh8 __attribute__((ext_vector_type(8)));
typedef float f4 __attribute__((ext_vector_type(4)));

// ---------------- degree / normalization / CSR build ----------------

__global__ void k_deg_count(const int* __restrict__ dst, int* __restrict__ deg) {
    int e = blockIdx.x * blockDim.x + threadIdx.x;
    if (e < N_EDGES) atomicAdd(&deg[dst[e]], 1);
}

__global__ void k_dinv(const int* __restrict__ deg, float* __restrict__ dinv) {
    int i = blockIdx.x * blockDim.x + threadIdx.x;
    if (i < N_NODES) dinv[i] = rsqrtf((float)deg[i] + 1.0f);  // +1 self-loop
}

#define SCAN_THREADS 1024
#define SCAN_CHUNK ((N_NODES + SCAN_THREADS - 1) / SCAN_THREADS)  // 49

__global__ __launch_bounds__(SCAN_THREADS)
void k_scan(const int* __restrict__ deg, int* __restrict__ row_start) {
    __shared__ int part[SCAN_THREADS];
    int t = threadIdx.x;
    int s0 = t * SCAN_CHUNK;
    int s1 = min(s0 + SCAN_CHUNK, N_NODES);
    int sum = 0;
    for (int i = s0; i < s1; ++i) sum += deg[i];
    part[t] = sum;
    __syncthreads();
    for (int off = 1; off < SCAN_THREADS; off <<= 1) {
        int v = (t >= off) ? part[t - off] : 0;
        __syncthreads();
        part[t] += v;
        __syncthreads();
    }
    int run = part[t] - sum;
    for (int i = s0; i < s1; ++i) { row_start[i] = run; run += deg[i]; }
    if (t == SCAN_THREADS - 1) row_start[N_NODES] = run;
}

__global__ void k_csr_fill(const int* __restrict__ src, const int* __restrict__ dst,
                           const int* __restrict__ row_start, int* __restrict__ cursor,
                           int* __restrict__ col) {
    int e = blockIdx.x * blockDim.x + threadIdx.x;
    if (e < N_EDGES) {
        int d = dst[e];
        int pos = atomicAdd(&cursor[d], 1);
        col[row_start[d] + pos] = src[e];
    }
}

// ---------------- bf16 hi/lo split helpers ----------------

__device__ __forceinline__ void split_bf16(float f, unsigned short& h, unsigned short& l) {
    unsigned int u = __float_as_uint(f);
    unsigned int hb = (u + 0x7FFFu + ((u >> 16) & 1u)) & 0xFFFF0000u;  // RNE
    h = (unsigned short)(hb >> 16);
    float rest = f - __uint_as_float(hb);
    unsigned int u2 = __float_as_uint(rest);
    l = (unsigned short)((u2 + 0x7FFFu + ((u2 >> 16) & 1u)) >> 16);
}

// Pre-split W[K x 256] into hi/lo global images in fragment-major layout:
// element (k,c) -> chunk s=k>>5, pos = s*8192 + ((c>>4)*4 + ((k>>3)&3))*128 + (c&15)*8 + (k&7)
__global__ void k_wsplit(const float* __restrict__ W, unsigned short* __restrict__ Bh,
                         unsigned short* __restrict__ Bl, int K) {
    int i = blockIdx.x * blockDim.x + threadIdx.x;
    if (i >= K * 256) return;
    int k = i >> 8, c = i & 255;
    unsigned short h, l;
    split_bf16(W[i], h, l);
    size_t pos = (size_t)(k >> 5) * 8192 + (size_t)(((c >> 4) * 4 + ((k >> 3) & 3)) * 128 + (c & 15) * 8 + (k & 7));
    Bh[pos] = h;
    Bl[pos] = l;
}

// ---------------- MFMA GEMM: C[M,256] = epilogue(A[M,K] @ B[K,256]) --------
// 64x256 tile per block, 4 waves (each 64x64), K-step 32, 3-pass hi/lo split.
// MODE 0: C = acc * dinv[row];  MODE 1: C = relu(acc + bias[col])

template<int MODE>
__global__ __launch_bounds__(256)
void k_gemm_mfma(const float* __restrict__ A, const unsigned short* __restrict__ Bh,
                 const unsigned short* __restrict__ Bl, const float* __restrict__ dinv,
                 const float* __restrict__ bias, float* __restrict__ C,
                 int M, int K) {
    __shared__ unsigned short AhL[2048], AlL[2048];   // 4KB each: 64x32 bf16 frag-major
    __shared__ unsigned short BhL[8192], BlL[8192];   // 16KB each: 32x256 bf16 frag-major

    const int tid = threadIdx.x;
    const int wv = tid >> 6, lane = tid & 63;
    const int m0 = blockIdx.x * 64;

    // A staging mapping: thread -> (row=tid>>2, kseg=tid&3 covering 8 k)
    const int arow = tid >> 2, aseg = tid & 3;
    const int agrow = m0 + arow;
    const bool aval = (agrow < M);
    const float* aptr = A + (size_t)agrow * K + aseg * 8;
    // frag-major A slot (16B units): (mi*4+g)*16 + r
    const int aslot = ((arow >> 4) * 4 + aseg) * 16 + (arow & 15);

    f4 acc[4][4];
    #pragma unroll
    for (int mi = 0; mi < 4; ++mi)
        #pragma unroll
        for (int nj = 0; nj < 4; ++nj)
            acc[mi][nj] = f4{0.f, 0.f, 0.f, 0.f};

    const int nsteps = K >> 5;
    for (int s = 0; s < nsteps; ++s) {
        // global loads to regs (no LDS yet)
        float4 va = make_float4(0.f, 0.f, 0.f, 0.f);
        float4 vb = make_float4(0.f, 0.f, 0.f, 0.f);
        if (aval) {
            va = *reinterpret_cast<const float4*>(aptr + s * 32);
            vb = *reinterpret_cast<const float4*>(aptr + s * 32 + 4);
        }
        sh8 bh[4], bl[4];
        {
            const unsigned short* gb = Bh + (size_t)s * 8192;
            const unsigned short* gl = Bl + (size_t)s * 8192;
            #pragma unroll
            for (int j = 0; j < 4; ++j) {
                bh[j] = *reinterpret_cast<const sh8*>(gb + j * 2048 + tid * 8);
                bl[j] = *reinterpret_cast<const sh8*>(gl + j * 2048 + tid * 8);
            }
        }
        __syncthreads();  // previous iteration's LDS reads complete

        // convert A regs -> hi/lo, write one b128 each
        {
            float f[8] = {va.x, va.y, va.z, va.w, vb.x, vb.y, vb.z, vb.w};
            sh8 hv, lv;
            #pragma unroll
            for (int e = 0; e < 8; ++e) {
                unsigned short h, l;
                split_bf16(f[e], h, l);
                hv[e] = (short)h;
                lv[e] = (short)l;
            }
            *reinterpret_cast<sh8*>(&AhL[aslot * 8]) = hv;
            *reinterpret_cast<sh8*>(&AlL[aslot * 8]) = lv;
        }
        // B: linear LDS image copy
        #pragma unroll
        for (int j = 0; j < 4; ++j) {
            *reinterpret_cast<sh8*>(&BhL[j * 2048 + tid * 8]) = bh[j];
            *reinterpret_cast<sh8*>(&BlL[j * 2048 + tid * 8]) = bl[j];
        }
        __syncthreads();

        // read fragments (all linear, conflict-free)
        sh8 afh[4], afl[4], bfh[4], bfl[4];
        #pragma unroll
        for (int mi = 0; mi < 4; ++mi) {
            afh[mi] = *reinterpret_cast<const sh8*>(&AhL[mi * 512 + lane * 8]);
            afl[mi] = *reinterpret_cast<const sh8*>(&AlL[mi * 512 + lane * 8]);
        }
        #pragma unroll
        for (int nj = 0; nj < 4; ++nj) {
            bfh[nj] = *reinterpret_cast<const sh8*>(&BhL[(wv * 4 + nj) * 512 + lane * 8]);
            bfl[nj] = *reinterpret_cast<const sh8*>(&BlL[(wv * 4 + nj) * 512 + lane * 8]);
        }
        #pragma unroll
        for (int mi = 0; mi < 4; ++mi) {
            #pragma unroll
            for (int nj = 0; nj < 4; ++nj) {
                acc[mi][nj] = __builtin_amdgcn_mfma_f32_16x16x32_bf16(afh[mi], bfh[nj], acc[mi][nj], 0, 0, 0);
                acc[mi][nj] = __builtin_amdgcn_mfma_f32_16x16x32_bf16(afh[mi], bfl[nj], acc[mi][nj], 0, 0, 0);
                acc[mi][nj] = __builtin_amdgcn_mfma_f32_16x16x32_bf16(afl[mi], bfh[nj], acc[mi][nj], 0, 0, 0);
            }
        }
    }

    // epilogue: D row = mi*16 + (lane>>4)*4 + q, col = wv*64 + nj*16 + (lane&15)
    #pragma unroll
    for (int mi = 0; mi < 4; ++mi) {
        #pragma unroll
        for (int q = 0; q < 4; ++q) {
            int grow = m0 + mi * 16 + (lane >> 4) * 4 + q;
            if (grow < M) {
                float dm = (MODE == 0) ? dinv[grow] : 0.f;
                #pragma unroll
                for (int nj = 0; nj < 4; ++nj) {
                    int gcol = wv * 64 + nj * 16 + (lane & 15);
                    float v = acc[mi][nj][q];
                    if (MODE == 0) v *= dm;
                    else          v = fmaxf(v + bias[gcol], 0.f);
                    C[(size_t)grow * 256 + gcol] = v;
                }
            }
        }
    }
}

// ---------------- aggregation ----------------

// layer-1 pre-aggregation in input space (128 dims, float2 per lane):
// z[n] = dinv[n] * ( dinv[n]*x[n] + sum_{s in N(n)} dinv[s]*x[s] )
__global__ __launch_bounds__(256)
void k_agg_x(const float* __restrict__ x, const int* __restrict__ row_start,
             const int* __restrict__ col, const float* __restrict__ dinv,
             float* __restrict__ z) {
    int wv = threadIdx.x >> 6, lane = threadIdx.x & 63;
    int n = blockIdx.x * 4 + wv;
    if (n >= N_NODES) return;
    const float2* x2 = (const float2*)x;
    float dn = dinv[n];
    float2 self = x2[(size_t)n * 64 + lane];
    float ax = self.x * dn, ay = self.y * dn;
    int e0 = row_start[n], e1 = row_start[n + 1];
    for (int e = e0; e < e1; ++e) {
        int s = col[e];
        float ds = dinv[s];
        float2 v = x2[(size_t)s * 64 + lane];
        ax += v.x * ds;
        ay += v.y * ds;
    }
    float2 o;
    o.x = ax * dn;
    o.y = ay * dn;
    ((float2*)z)[(size_t)n * 64 + lane] = o;
}

// layer-2 aggregation: y pre-scaled by dinv[src] (GEMM2 epilogue).
// out[n] = relu(dinv[n]*(y[n] + sum y[col]) + b)
__global__ __launch_bounds__(256)
void k_agg_csr(const float* __restrict__ y, const int* __restrict__ row_start,
               const int* __restrict__ col, const float* __restrict__ dinv,
               const float* __restrict__ bias, float* __restrict__ out) {
    int wv = threadIdx.x >> 6, lane = threadIdx.x & 63;
    int n = blockIdx.x * 4 + wv;
    if (n >= N_NODES) return;
    const float4* y4 = (const float4*)y;
    float4 acc = y4[(size_t)n * 64 + lane];
    int e0 = row_start[n], e1 = row_start[n + 1];
    for (int e = e0; e < e1; ++e) {
        int s = col[e];
        float4 v = y4[(size_t)s * 64 + lane];
        acc.x += v.x; acc.y += v.y; acc.z += v.z; acc.w += v.w;
    }
    float dn = dinv[n];
    float4 b = ((const float4*)bias)[lane];
    float4 o;
    o.x = fmaxf(acc.x * dn + b.x, 0.f);
    o.y = fmaxf(acc.y * dn + b.y, 0.f);
    o.z = fmaxf(acc.z * dn + b.z, 0.f);
    o.w = fmaxf(acc.w * dn + b.w, 0.f);
    ((float4*)out)[(size_t)n * 64 + lane] = o;
}

// ---------------- pooling + FC ----------------

__global__ void k_bounds(const int* __restrict__ batch, int* __restrict__ bounds) {
    int g = blockIdx.x * blockDim.x + threadIdx.x;
    if (g > N_GRAPHS) return;
    int lo = 0, hi = N_NODES;
    while (lo < hi) {
        int mid = (lo + hi) >> 1;
        if (batch[mid] < g) lo = mid + 1; else hi = mid;
    }
    bounds[g] = lo;
}

__global__ void k_sums_init(float* __restrict__ sums) {
    int i = blockIdx.x * blockDim.x + threadIdx.x;
    if (i < N_GRAPHS * HID_DIM) sums[i] = 0.0f;
}

__global__ void k_pool(const float* __restrict__ h, const int* __restrict__ bounds,
                       float* __restrict__ sums) {
    int g = blockIdx.x / POOL_CHUNKS;
    int chunk = blockIdx.x % POOL_CHUNKS;
    int c = threadIdx.x;
    int s = bounds[g], e = bounds[g + 1];
    int len = e - s;
    if (len <= 0) return;
    int per = (len + POOL_CHUNKS - 1) / POOL_CHUNKS;
    int ns = s + chunk * per;
    int ne = min(ns + per, e);
    if (ns >= ne) return;
    float sum = 0.0f;
    for (int n = ns; n < ne; ++n) sum += h[(size_t)n * HID_DIM + c];
    atomicAdd(&sums[g * HID_DIM + c], sum);
}

__global__ void k_final(const float* __restrict__ sums, const int* __restrict__ bounds,
                        const float* __restrict__ Wfc, const float* __restrict__ bfc,
                        float* __restrict__ out) {
    __shared__ float red[HID_DIM];
    int g = blockIdx.x;
    int c = threadIdx.x;
    float cnt = (float)(bounds[g + 1] - bounds[g]);
    float v = sums[g * HID_DIM + c] / fmaxf(cnt, 1.0f) * Wfc[c];
    red[c] = v;
    __syncthreads();
    for (int s = HID_DIM / 2; s > 0; s >>= 1) {
        if (c < s) red[c] += red[c + s];
        __syncthreads();
    }
    if (c == 0) out[g] = red[0] + bfc[0];
}

// ---------------- launch ----------------

extern "C" void kernel_launch(void* const* d_in, const int* in_sizes, int n_in,
                              void* d_out, int out_size, void* d_ws, size_t ws_size,
                              hipStream_t stream) {
    const float* x    = (const float*)d_in[0];
    const int*   ei   = (const int*)d_in[1];
    const int*   batch= (const int*)d_in[2];
    const float* W1   = (const float*)d_in[3];
    const float* b1   = (const float*)d_in[4];
    const float* W2   = (const float*)d_in[5];
    const float* b2   = (const float*)d_in[6];
    const float* Wfc  = (const float*)d_in[7];
    const float* bfc  = (const float*)d_in[8];
    float* out = (float*)d_out;

    const int* src = ei;
    const int* dst = ei + N_EDGES;

    char* ws = (char*)d_ws;
    const size_t BUF_BYTES = (size_t)N_NODES * HID_DIM * sizeof(float);  // 51.2 MB
    size_t off = 0;
    float* region0   = (float*)(ws + off); off += BUF_BYTES;   // h1, then h2
    float* region1   = (float*)(ws + off); off += BUF_BYTES;   // z (front 25.6MB), then y2
    int*   deg_i     = (int*)  (ws + off); off += 200704;
    int*   cursor    = (int*)  (ws + off); off += 200704;
    float* dinv      = (float*)(ws + off); off += 200704;
    int*   row_start = (int*)  (ws + off); off += 200704;
    int*   col       = (int*)  (ws + off); off += (size_t)N_EDGES * 4;
    unsigned short* Bh1 = (unsigned short*)(ws + off); off += 65536;
    unsigned short* Bl1 = (unsigned short*)(ws + off); off += 65536;
    unsigned short* Bh2 = (unsigned short*)(ws + off); off += 131072;
    unsigned short* Bl2 = (unsigned short*)(ws + off); off += 131072;
    float* sums      = (float*)(ws + off); off += 65536;
    int*   bounds    = (int*)  (ws + off); off += 512;
    (void)ws_size; (void)in_sizes; (void)n_in; (void)out_size;

    float* z  = region1;   // [N, 128]
    float* h1 = region0;   // [N, 256]
    float* y2 = region1;   // [N, 256] (z dead after GEMM1)
    float* h2 = region0;   // [N, 256] (h1 dead after GEMM2)

    // 1. CSR build + dinv + weight split
    hipMemsetAsync(deg_i, 0, 2 * 200704, stream);
    k_deg_count<<<(N_EDGES + 255) / 256, 256, 0, stream>>>(dst, deg_i);
    k_dinv<<<(N_NODES + 255) / 256, 256, 0, stream>>>(deg_i, dinv);
    k_scan<<<1, SCAN_THREADS, 0, stream>>>(deg_i, row_start);
    k_csr_fill<<<(N_EDGES + 255) / 256, 256, 0, stream>>>(src, dst, row_start, cursor, col);
    k_wsplit<<<(IN_DIM * 256 + 255) / 256, 256, 0, stream>>>(W1, Bh1, Bl1, IN_DIM);
    k_wsplit<<<(HID_DIM * 256 + 255) / 256, 256, 0, stream>>>(W2, Bh2, Bl2, HID_DIM);

    const int gemm_grid = (N_NODES + 63) / 64;  // 782

    // 2. layer 1: z = A_hat @ x ; h1 = relu(z @ W1 + b1)
    k_agg_x<<<(N_NODES + 3) / 4, 256, 0, stream>>>(x, row_start, col, dinv, z);
    k_gemm_mfma<1><<<gemm_grid, 256, 0, stream>>>(z, Bh1, Bl1, dinv, b1, h1, N_NODES, IN_DIM);

    // 3. layer 2: y2 = (h1 @ W2) * dinv ; h2 = relu(A_hat-gather + b2)
    k_gemm_mfma<0><<<gemm_grid, 256, 0, stream>>>(h1, Bh2, Bl2, dinv, b2, y2, N_NODES, HID_DIM);
    k_agg_csr<<<(N_NODES + 3) / 4, 256, 0, stream>>>(y2, row_start, col, dinv, b2, h2);

    // 4. pool + fc
    k_bounds<<<1, 128, 0, stream>>>(batch, bounds);
    k_sums_init<<<(N_GRAPHS * HID_DIM + 255) / 256, 256, 0, stream>>>(sums);
    k_pool<<<N_GRAPHS * POOL_CHUNKS, HID_DIM, 0, stream>>>(h2, bounds, sums);
    k_final<<<N_GRAPHS, HID_DIM, 0, stream>>>(sums, bounds, Wfc, bfc, out);
}

// Round 4
// 436.699 us; speedup vs baseline: 3.8197x; 1.0656x over previous
//
#include <hip/hip_runtime.h>
#include <hip/hip_bf16.h>

#define N_NODES 50000
#define N_EDGES 800000
#define N_GRAPHS 64
#define IN_DIM 128
#define HID_DIM 256
#define POOL_CHUNKS 16

typedef short sh8 __attribute__((ext_vector_type(8)));
typedef float f4 __attribute__((ext_vector_type(4)));
typedef unsigned short us2 __attribute__((ext_vector_type(2)));
typedef unsigned short us4 __attribute__((ext_vector_type(4)));

__device__ __forceinline__ unsigned short bf16rne(float f) {
    unsigned int u = __float_as_uint(f);
    return (unsigned short)((u + 0x7FFFu + ((u >> 16) & 1u)) >> 16);
}
__device__ __forceinline__ float bf2f(unsigned short b) {
    return __uint_as_float((unsigned int)b << 16);
}

// ---------------- degree / normalization / CSR build ----------------

__global__ void k_deg_count(const int* __restrict__ dst, int* __restrict__ deg) {
    int e = blockIdx.x * blockDim.x + threadIdx.x;
    if (e < N_EDGES) atomicAdd(&deg[dst[e]], 1);
}

__global__ void k_dinv(const int* __restrict__ deg, float* __restrict__ dinv) {
    int i = blockIdx.x * blockDim.x + threadIdx.x;
    if (i < N_NODES) dinv[i] = rsqrtf((float)deg[i] + 1.0f);  // +1 self-loop
}

#define SCAN_THREADS 1024
#define SCAN_CHUNK ((N_NODES + SCAN_THREADS - 1) / SCAN_THREADS)  // 49

__global__ __launch_bounds__(SCAN_THREADS)
void k_scan(const int* __restrict__ deg, int* __restrict__ row_start) {
    __shared__ int part[SCAN_THREADS];
    int t = threadIdx.x;
    int s0 = t * SCAN_CHUNK;
    int s1 = min(s0 + SCAN_CHUNK, N_NODES);
    int sum = 0;
    for (int i = s0; i < s1; ++i) sum += deg[i];
    part[t] = sum;
    __syncthreads();
    for (int off = 1; off < SCAN_THREADS; off <<= 1) {
        int v = (t >= off) ? part[t - off] : 0;
        __syncthreads();
        part[t] += v;
        __syncthreads();
    }
    int run = part[t] - sum;
    for (int i = s0; i < s1; ++i) { row_start[i] = run; run += deg[i]; }
    if (t == SCAN_THREADS - 1) row_start[N_NODES] = run;
}

__global__ void k_csr_fill(const int* __restrict__ src, const int* __restrict__ dst,
                           const int* __restrict__ row_start, int* __restrict__ cursor,
                           int* __restrict__ col) {
    int e = blockIdx.x * blockDim.x + threadIdx.x;
    if (e < N_EDGES) {
        int d = dst[e];
        int pos = atomicAdd(&cursor[d], 1);
        col[row_start[d] + pos] = src[e];
    }
}

// ---------------- bf16 hi/lo split helpers ----------------

__device__ __forceinline__ void split_bf16(float f, unsigned short& h, unsigned short& l) {
    unsigned int u = __float_as_uint(f);
    unsigned int hb = (u + 0x7FFFu + ((u >> 16) & 1u)) & 0xFFFF0000u;  // RNE
    h = (unsigned short)(hb >> 16);
    float rest = f - __uint_as_float(hb);
    unsigned int u2 = __float_as_uint(rest);
    l = (unsigned short)((u2 + 0x7FFFu + ((u2 >> 16) & 1u)) >> 16);
}

// x (fp32) -> bf16 plane, 4 elements per thread
__global__ void k_x2bf(const float* __restrict__ x, unsigned short* __restrict__ xb) {
    int i = blockIdx.x * blockDim.x + threadIdx.x;
    if (i >= N_NODES * IN_DIM / 4) return;
    float4 v = ((const float4*)x)[i];
    us4 o;
    o.x = bf16rne(v.x); o.y = bf16rne(v.y); o.z = bf16rne(v.z); o.w = bf16rne(v.w);
    ((us4*)xb)[i] = o;
}

// Pre-split W[K x 256] into hi/lo global images in fragment-major layout:
// element (k,c) -> chunk s=k>>5, pos = s*8192 + ((c>>4)*4 + ((k>>3)&3))*128 + (c&15)*8 + (k&7)
__global__ void k_wsplit(const float* __restrict__ W, unsigned short* __restrict__ Bh,
                         unsigned short* __restrict__ Bl, int K) {
    int i = blockIdx.x * blockDim.x + threadIdx.x;
    if (i >= K * 256) return;
    int k = i >> 8, c = i & 255;
    unsigned short h, l;
    split_bf16(W[i], h, l);
    size_t pos = (size_t)(k >> 5) * 8192 + (size_t)(((c >> 4) * 4 + ((k >> 3) & 3)) * 128 + (c & 15) * 8 + (k & 7));
    Bh[pos] = h;
    Bl[pos] = l;
}

// ---------------- MFMA GEMM: [M,256] = epilogue(A[M,K] @ B[K,256]) --------
// 64x256 tile per block, 4 waves (each 64x64), K-step 32, 3-pass hi/lo split.
// MODE 0: Yb[m,c] = bf16(acc * dinv[m])   (bf16 gather plane for layer-2 agg)
// MODE 1: C[m,c]  = relu(acc + bias[c])   (fp32)

template<int MODE>
__global__ __launch_bounds__(256)
void k_gemm_mfma(const float* __restrict__ A, const unsigned short* __restrict__ Bh,
                 const unsigned short* __restrict__ Bl, const float* __restrict__ dinv,
                 const float* __restrict__ bias, float* __restrict__ C,
                 unsigned short* __restrict__ Yb, int M, int K) {
    __shared__ unsigned short AhL[2048], AlL[2048];   // 4KB each: 64x32 bf16 frag-major
    __shared__ unsigned short BhL[8192], BlL[8192];   // 16KB each: 32x256 bf16 frag-major

    const int tid = threadIdx.x;
    const int wv = tid >> 6, lane = tid & 63;
    const int m0 = blockIdx.x * 64;

    const int arow = tid >> 2, aseg = tid & 3;
    const int agrow = m0 + arow;
    const bool aval = (agrow < M);
    const float* aptr = A + (size_t)agrow * K + aseg * 8;
    const int aslot = ((arow >> 4) * 4 + aseg) * 16 + (arow & 15);

    f4 acc[4][4];
    #pragma unroll
    for (int mi = 0; mi < 4; ++mi)
        #pragma unroll
        for (int nj = 0; nj < 4; ++nj)
            acc[mi][nj] = f4{0.f, 0.f, 0.f, 0.f};

    const int nsteps = K >> 5;
    for (int s = 0; s < nsteps; ++s) {
        float4 va = make_float4(0.f, 0.f, 0.f, 0.f);
        float4 vb = make_float4(0.f, 0.f, 0.f, 0.f);
        if (aval) {
            va = *reinterpret_cast<const float4*>(aptr + s * 32);
            vb = *reinterpret_cast<const float4*>(aptr + s * 32 + 4);
        }
        sh8 bh[4], bl[4];
        {
            const unsigned short* gb = Bh + (size_t)s * 8192;
            const unsigned short* gl = Bl + (size_t)s * 8192;
            #pragma unroll
            for (int j = 0; j < 4; ++j) {
                bh[j] = *reinterpret_cast<const sh8*>(gb + j * 2048 + tid * 8);
                bl[j] = *reinterpret_cast<const sh8*>(gl + j * 2048 + tid * 8);
            }
        }
        __syncthreads();

        {
            float f[8] = {va.x, va.y, va.z, va.w, vb.x, vb.y, vb.z, vb.w};
            sh8 hv, lv;
            #pragma unroll
            for (int e = 0; e < 8; ++e) {
                unsigned short h, l;
                split_bf16(f[e], h, l);
                hv[e] = (short)h;
                lv[e] = (short)l;
            }
            *reinterpret_cast<sh8*>(&AhL[aslot * 8]) = hv;
            *reinterpret_cast<sh8*>(&AlL[aslot * 8]) = lv;
        }
        #pragma unroll
        for (int j = 0; j < 4; ++j) {
            *reinterpret_cast<sh8*>(&BhL[j * 2048 + tid * 8]) = bh[j];
            *reinterpret_cast<sh8*>(&BlL[j * 2048 + tid * 8]) = bl[j];
        }
        __syncthreads();

        sh8 afh[4], afl[4], bfh[4], bfl[4];
        #pragma unroll
        for (int mi = 0; mi < 4; ++mi) {
            afh[mi] = *reinterpret_cast<const sh8*>(&AhL[mi * 512 + lane * 8]);
            afl[mi] = *reinterpret_cast<const sh8*>(&AlL[mi * 512 + lane * 8]);
        }
        #pragma unroll
        for (int nj = 0; nj < 4; ++nj) {
            bfh[nj] = *reinterpret_cast<const sh8*>(&BhL[(wv * 4 + nj) * 512 + lane * 8]);
            bfl[nj] = *reinterpret_cast<const sh8*>(&BlL[(wv * 4 + nj) * 512 + lane * 8]);
        }
        #pragma unroll
        for (int mi = 0; mi < 4; ++mi) {
            #pragma unroll
            for (int nj = 0; nj < 4; ++nj) {
                acc[mi][nj] = __builtin_amdgcn_mfma_f32_16x16x32_bf16(afh[mi], bfh[nj], acc[mi][nj], 0, 0, 0);
                acc[mi][nj] = __builtin_amdgcn_mfma_f32_16x16x32_bf16(afh[mi], bfl[nj], acc[mi][nj], 0, 0, 0);
                acc[mi][nj] = __builtin_amdgcn_mfma_f32_16x16x32_bf16(afl[mi], bfh[nj], acc[mi][nj], 0, 0, 0);
            }
        }
    }

    #pragma unroll
    for (int mi = 0; mi < 4; ++mi) {
        #pragma unroll
        for (int q = 0; q < 4; ++q) {
            int grow = m0 + mi * 16 + (lane >> 4) * 4 + q;
            if (grow < M) {
                float dm = (MODE == 0) ? dinv[grow] : 0.f;
                #pragma unroll
                for (int nj = 0; nj < 4; ++nj) {
                    int gcol = wv * 64 + nj * 16 + (lane & 15);
                    float v = acc[mi][nj][q];
                    if (MODE == 0) {
                        Yb[(size_t)grow * 256 + gcol] = bf16rne(v * dm);
                    } else {
                        C[(size_t)grow * 256 + gcol] = fmaxf(v + bias[gcol], 0.f);
                    }
                }
            }
        }
    }
}

// ---------------- aggregation ----------------

// layer-1: z[n] = dinv[n] * ( dinv[n]*x[n] + sum dinv[s]*xb[s] )
// self term fp32, neighbor gathers bf16 (256 B/row)
__global__ __launch_bounds__(256)
void k_agg_x(const float* __restrict__ x, const unsigned short* __restrict__ xb,
             const int* __restrict__ row_start, const int* __restrict__ col,
             const float* __restrict__ dinv, float* __restrict__ z) {
    int wv = threadIdx.x >> 6, lane = threadIdx.x & 63;
    int n = blockIdx.x * 4 + wv;
    if (n >= N_NODES) return;
    float dn = dinv[n];
    const float2* x2 = (const float2*)x;
    float2 self = x2[(size_t)n * 64 + lane];
    float ax = self.x * dn, ay = self.y * dn;
    const us2* xb2 = (const us2*)xb;
    int e0 = row_start[n], e1 = row_start[n + 1];
    for (int e = e0; e < e1; ++e) {
        int s = col[e];
        float ds = dinv[s];
        us2 v = xb2[(size_t)s * 64 + lane];
        ax += bf2f(v.x) * ds;
        ay += bf2f(v.y) * ds;
    }
    float2 o;
    o.x = ax * dn;
    o.y = ay * dn;
    ((float2*)z)[(size_t)n * 64 + lane] = o;
}

// layer-2: yb pre-scaled by dinv[src], bf16 (512 B/row gathers).
// out[n] = relu(dinv[n]*(yb[n] + sum yb[col]) + b)  (fp32 accumulate)
__global__ __launch_bounds__(256)
void k_agg_csr(const unsigned short* __restrict__ yb, const int* __restrict__ row_start,
               const int* __restrict__ col, const float* __restrict__ dinv,
               const float* __restrict__ bias, float* __restrict__ out) {
    int wv = threadIdx.x >> 6, lane = threadIdx.x & 63;
    int n = blockIdx.x * 4 + wv;
    if (n >= N_NODES) return;
    const us4* y4 = (const us4*)yb;
    us4 sv = y4[(size_t)n * 64 + lane];
    float a0 = bf2f(sv.x), a1 = bf2f(sv.y), a2 = bf2f(sv.z), a3 = bf2f(sv.w);
    int e0 = row_start[n], e1 = row_start[n + 1];
    for (int e = e0; e < e1; ++e) {
        int s = col[e];
        us4 v = y4[(size_t)s * 64 + lane];
        a0 += bf2f(v.x); a1 += bf2f(v.y); a2 += bf2f(v.z); a3 += bf2f(v.w);
    }
    float dn = dinv[n];
    float4 b = ((const float4*)bias)[lane];
    float4 o;
    o.x = fmaxf(a0 * dn + b.x, 0.f);
    o.y = fmaxf(a1 * dn + b.y, 0.f);
    o.z = fmaxf(a2 * dn + b.z, 0.f);
    o.w = fmaxf(a3 * dn + b.w, 0.f);
    ((float4*)out)[(size_t)n * 64 + lane] = o;
}

// ---------------- pooling + FC ----------------

__global__ void k_bounds(const int* __restrict__ batch, int* __restrict__ bounds) {
    int g = blockIdx.x * blockDim.x + threadIdx.x;
    if (g > N_GRAPHS) return;
    int lo = 0, hi = N_NODES;
    while (lo < hi) {
        int mid = (lo + hi) >> 1;
        if (batch[mid] < g) lo = mid + 1; else hi = mid;
    }
    bounds[g] = lo;
}

__global__ void k_sums_init(float* __restrict__ sums) {
    int i = blockIdx.x * blockDim.x + threadIdx.x;
    if (i < N_GRAPHS * HID_DIM) sums[i] = 0.0f;
}

__global__ void k_pool(const float* __restrict__ h, const int* __restrict__ bounds,
                       float* __restrict__ sums) {
    int g = blockIdx.x / POOL_CHUNKS;
    int chunk = blockIdx.x % POOL_CHUNKS;
    int c = threadIdx.x;
    int s = bounds[g], e = bounds[g + 1];
    int len = e - s;
    if (len <= 0) return;
    int per = (len + POOL_CHUNKS - 1) / POOL_CHUNKS;
    int ns = s + chunk * per;
    int ne = min(ns + per, e);
    if (ns >= ne) return;
    float sum = 0.0f;
    for (int n = ns; n < ne; ++n) sum += h[(size_t)n * HID_DIM + c];
    atomicAdd(&sums[g * HID_DIM + c], sum);
}

__global__ void k_final(const float* __restrict__ sums, const int* __restrict__ bounds,
                        const float* __restrict__ Wfc, const float* __restrict__ bfc,
                        float* __restrict__ out) {
    __shared__ float red[HID_DIM];
    int g = blockIdx.x;
    int c = threadIdx.x;
    float cnt = (float)(bounds[g + 1] - bounds[g]);
    float v = sums[g * HID_DIM + c] / fmaxf(cnt, 1.0f) * Wfc[c];
    red[c] = v;
    __syncthreads();
    for (int s = HID_DIM / 2; s > 0; s >>= 1) {
        if (c < s) red[c] += red[c + s];
        __syncthreads();
    }
    if (c == 0) out[g] = red[0] + bfc[0];
}

// ---------------- launch ----------------

extern "C" void kernel_launch(void* const* d_in, const int* in_sizes, int n_in,
                              void* d_out, int out_size, void* d_ws, size_t ws_size,
                              hipStream_t stream) {
    const float* x    = (const float*)d_in[0];
    const int*   ei   = (const int*)d_in[1];
    const int*   batch= (const int*)d_in[2];
    const float* W1   = (const float*)d_in[3];
    const float* b1   = (const float*)d_in[4];
    const float* W2   = (const float*)d_in[5];
    const float* b2   = (const float*)d_in[6];
    const float* Wfc  = (const float*)d_in[7];
    const float* bfc  = (const float*)d_in[8];
    float* out = (float*)d_out;

    const int* src = ei;
    const int* dst = ei + N_EDGES;

    char* ws = (char*)d_ws;
    const size_t BUF_BYTES = (size_t)N_NODES * HID_DIM * sizeof(float);  // 51.2 MB
    size_t off = 0;
    float* region0   = (float*)(ws + off); off += BUF_BYTES;   // h1, then h2
    char*  region1   = (char*) (ws + off); off += BUF_BYTES;   // z/y2b front, xb back
    int*   deg_i     = (int*)  (ws + off); off += 200704;
    int*   cursor    = (int*)  (ws + off); off += 200704;
    float* dinv      = (float*)(ws + off); off += 200704;
    int*   row_start = (int*)  (ws + off); off += 200704;
    int*   col       = (int*)  (ws + off); off += (size_t)N_EDGES * 4;
    unsigned short* Bh1 = (unsigned short*)(ws + off); off += 65536;
    unsigned short* Bl1 = (unsigned short*)(ws + off); off += 65536;
    unsigned short* Bh2 = (unsigned short*)(ws + off); off += 131072;
    unsigned short* Bl2 = (unsigned short*)(ws + off); off += 131072;
    float* sums      = (float*)(ws + off); off += 65536;
    int*   bounds    = (int*)  (ws + off); off += 512;
    (void)ws_size; (void)in_sizes; (void)n_in; (void)out_size;

    // region1 overlays (lifetimes disjoint):
    //   z   [N,128] fp32 : front 25.6 MB — written by agg_x, read by GEMM1, then dead
    //   y2b [N,256] bf16 : front 25.6 MB — written by GEMM2, read by agg_csr
    //   xb  [N,128] bf16 : back  12.8 MB — written by x2bf, read by agg_x, then dead
    float*          z   = (float*)region1;
    unsigned short* y2b = (unsigned short*)region1;
    unsigned short* xb  = (unsigned short*)(region1 + (size_t)N_NODES * IN_DIM * sizeof(float));
    float* h1 = region0;
    float* h2 = region0;

    // 1. CSR build + dinv + weight split + x->bf16
    hipMemsetAsync(deg_i, 0, 2 * 200704, stream);
    k_deg_count<<<(N_EDGES + 255) / 256, 256, 0, stream>>>(dst, deg_i);
    k_dinv<<<(N_NODES + 255) / 256, 256, 0, stream>>>(deg_i, dinv);
    k_scan<<<1, SCAN_THREADS, 0, stream>>>(deg_i, row_start);
    k_csr_fill<<<(N_EDGES + 255) / 256, 256, 0, stream>>>(src, dst, row_start, cursor, col);
    k_x2bf<<<(N_NODES * IN_DIM / 4 + 255) / 256, 256, 0, stream>>>(x, xb);
    k_wsplit<<<(IN_DIM * 256 + 255) / 256, 256, 0, stream>>>(W1, Bh1, Bl1, IN_DIM);
    k_wsplit<<<(HID_DIM * 256 + 255) / 256, 256, 0, stream>>>(W2, Bh2, Bl2, HID_DIM);

    const int gemm_grid = (N_NODES + 63) / 64;  // 782

    // 2. layer 1: z = A_hat @ x ; h1 = relu(z @ W1 + b1)
    k_agg_x<<<(N_NODES + 3) / 4, 256, 0, stream>>>(x, xb, row_start, col, dinv, z);
    k_gemm_mfma<1><<<gemm_grid, 256, 0, stream>>>(z, Bh1, Bl1, dinv, b1, h1, nullptr, N_NODES, IN_DIM);

    // 3. layer 2: y2b = bf16((h1 @ W2) * dinv) ; h2 = relu(gather + b2)
    k_gemm_mfma<0><<<gemm_grid, 256, 0, stream>>>(h1, Bh2, Bl2, dinv, b2, nullptr, y2b, N_NODES, HID_DIM);
    k_agg_csr<<<(N_NODES + 3) / 4, 256, 0, stream>>>(y2b, row_start, col, dinv, b2, h2);

    // 4. pool + fc
    k_bounds<<<1, 128, 0, stream>>>(batch, bounds);
    k_sums_init<<<(N_GRAPHS * HID_DIM + 255) / 256, 256, 0, stream>>>(sums);
    k_pool<<<N_GRAPHS * POOL_CHUNKS, HID_DIM, 0, stream>>>(h2, bounds, sums);
    k_final<<<N_GRAPHS, HID_DIM, 0, stream>>>(sums, bounds, Wfc, bfc, out);
}

// Round 5
// 400.643 us; speedup vs baseline: 4.1635x; 1.0900x over previous
//
#include <hip/hip_runtime.h>
#include <hip/hip_bf16.h>

#define N_NODES 50000
#define N_EDGES 800000
#define N_GRAPHS 64
#define IN_DIM 128
#define HID_DIM 256

typedef short sh8 __attribute__((ext_vector_type(8)));
typedef float f4 __attribute__((ext_vector_type(4)));
typedef unsigned short us4 __attribute__((ext_vector_type(4)));
typedef unsigned short us8 __attribute__((ext_vector_type(8)));

__device__ __forceinline__ unsigned short bf16rne(float f) {
    unsigned int u = __float_as_uint(f);
    return (unsigned short)((u + 0x7FFFu + ((u >> 16) & 1u)) >> 16);
}
__device__ __forceinline__ float bf2f(unsigned short b) {
    return __uint_as_float((unsigned int)b << 16);
}

// ---------------- degree / normalization / CSR build ----------------

__global__ void k_deg_count(const int* __restrict__ dst, int* __restrict__ deg) {
    int e = blockIdx.x * blockDim.x + threadIdx.x;
    if (e < N_EDGES) atomicAdd(&deg[dst[e]], 1);
}

__global__ void k_dinv(const int* __restrict__ deg, float* __restrict__ dinv) {
    int i = blockIdx.x * blockDim.x + threadIdx.x;
    if (i < N_NODES) dinv[i] = rsqrtf((float)deg[i] + 1.0f);  // +1 self-loop
}

#define SCAN_THREADS 1024
#define SCAN_CHUNK ((N_NODES + SCAN_THREADS - 1) / SCAN_THREADS)  // 49

__global__ __launch_bounds__(SCAN_THREADS)
void k_scan(const int* __restrict__ deg, int* __restrict__ row_start) {
    __shared__ int part[SCAN_THREADS];
    int t = threadIdx.x;
    int s0 = t * SCAN_CHUNK;
    int s1 = min(s0 + SCAN_CHUNK, N_NODES);
    int sum = 0;
    for (int i = s0; i < s1; ++i) sum += deg[i];
    part[t] = sum;
    __syncthreads();
    for (int off = 1; off < SCAN_THREADS; off <<= 1) {
        int v = (t >= off) ? part[t - off] : 0;
        __syncthreads();
        part[t] += v;
        __syncthreads();
    }
    int run = part[t] - sum;
    for (int i = s0; i < s1; ++i) { row_start[i] = run; run += deg[i]; }
    if (t == SCAN_THREADS - 1) row_start[N_NODES] = run;
}

__global__ void k_csr_fill(const int* __restrict__ src, const int* __restrict__ dst,
                           const int* __restrict__ row_start, int* __restrict__ cursor,
                           int* __restrict__ col) {
    int e = blockIdx.x * blockDim.x + threadIdx.x;
    if (e < N_EDGES) {
        int d = dst[e];
        int pos = atomicAdd(&cursor[d], 1);
        col[row_start[d] + pos] = src[e];
    }
}

// ---------------- bf16 hi/lo split helpers ----------------

__device__ __forceinline__ void split_bf16(float f, unsigned short& h, unsigned short& l) {
    unsigned int u = __float_as_uint(f);
    unsigned int hb = (u + 0x7FFFu + ((u >> 16) & 1u)) & 0xFFFF0000u;  // RNE
    h = (unsigned short)(hb >> 16);
    float rest = f - __uint_as_float(hb);
    unsigned int u2 = __float_as_uint(rest);
    l = (unsigned short)((u2 + 0x7FFFu + ((u2 >> 16) & 1u)) >> 16);
}

// x (fp32) -> bf16 plane, 4 elements per thread
__global__ void k_x2bf(const float* __restrict__ x, unsigned short* __restrict__ xb) {
    int i = blockIdx.x * blockDim.x + threadIdx.x;
    if (i >= N_NODES * IN_DIM / 4) return;
    float4 v = ((const float4*)x)[i];
    us4 o;
    o.x = bf16rne(v.x); o.y = bf16rne(v.y); o.z = bf16rne(v.z); o.w = bf16rne(v.w);
    ((us4*)xb)[i] = o;
}

// Pre-split W[K x 256] into hi/lo global images in fragment-major layout
__global__ void k_wsplit(const float* __restrict__ W, unsigned short* __restrict__ Bh,
                         unsigned short* __restrict__ Bl, int K) {
    int i = blockIdx.x * blockDim.x + threadIdx.x;
    if (i >= K * 256) return;
    int k = i >> 8, c = i & 255;
    unsigned short h, l;
    split_bf16(W[i], h, l);
    size_t pos = (size_t)(k >> 5) * 8192 + (size_t)(((c >> 4) * 4 + ((k >> 3) & 3)) * 128 + (c & 15) * 8 + (k & 7));
    Bh[pos] = h;
    Bl[pos] = l;
}

// ---------------- MFMA GEMM: [M,256] = epilogue(A[M,K] @ B[K,256]) --------
// 64x256 tile per block, 4 waves (each 64x64), K-step 32, 3-pass hi/lo split.
// MODE 0: Yb[m,c] = bf16(acc * dinv[m]);  MODE 1: C[m,c] = relu(acc + bias[c])

template<int MODE>
__global__ __launch_bounds__(256)
void k_gemm_mfma(const float* __restrict__ A, const unsigned short* __restrict__ Bh,
                 const unsigned short* __restrict__ Bl, const float* __restrict__ dinv,
                 const float* __restrict__ bias, float* __restrict__ C,
                 unsigned short* __restrict__ Yb, int M, int K) {
    __shared__ unsigned short AhL[2048], AlL[2048];
    __shared__ unsigned short BhL[8192], BlL[8192];

    const int tid = threadIdx.x;
    const int wv = tid >> 6, lane = tid & 63;
    const int m0 = blockIdx.x * 64;

    const int arow = tid >> 2, aseg = tid & 3;
    const int agrow = m0 + arow;
    const bool aval = (agrow < M);
    const float* aptr = A + (size_t)agrow * K + aseg * 8;
    const int aslot = ((arow >> 4) * 4 + aseg) * 16 + (arow & 15);

    f4 acc[4][4];
    #pragma unroll
    for (int mi = 0; mi < 4; ++mi)
        #pragma unroll
        for (int nj = 0; nj < 4; ++nj)
            acc[mi][nj] = f4{0.f, 0.f, 0.f, 0.f};

    const int nsteps = K >> 5;
    for (int s = 0; s < nsteps; ++s) {
        float4 va = make_float4(0.f, 0.f, 0.f, 0.f);
        float4 vb = make_float4(0.f, 0.f, 0.f, 0.f);
        if (aval) {
            va = *reinterpret_cast<const float4*>(aptr + s * 32);
            vb = *reinterpret_cast<const float4*>(aptr + s * 32 + 4);
        }
        sh8 bh[4], bl[4];
        {
            const unsigned short* gb = Bh + (size_t)s * 8192;
            const unsigned short* gl = Bl + (size_t)s * 8192;
            #pragma unroll
            for (int j = 0; j < 4; ++j) {
                bh[j] = *reinterpret_cast<const sh8*>(gb + j * 2048 + tid * 8);
                bl[j] = *reinterpret_cast<const sh8*>(gl + j * 2048 + tid * 8);
            }
        }
        __syncthreads();

        {
            float f[8] = {va.x, va.y, va.z, va.w, vb.x, vb.y, vb.z, vb.w};
            sh8 hv, lv;
            #pragma unroll
            for (int e = 0; e < 8; ++e) {
                unsigned short h, l;
                split_bf16(f[e], h, l);
                hv[e] = (short)h;
                lv[e] = (short)l;
            }
            *reinterpret_cast<sh8*>(&AhL[aslot * 8]) = hv;
            *reinterpret_cast<sh8*>(&AlL[aslot * 8]) = lv;
        }
        #pragma unroll
        for (int j = 0; j < 4; ++j) {
            *reinterpret_cast<sh8*>(&BhL[j * 2048 + tid * 8]) = bh[j];
            *reinterpret_cast<sh8*>(&BlL[j * 2048 + tid * 8]) = bl[j];
        }
        __syncthreads();

        sh8 afh[4], afl[4], bfh[4], bfl[4];
        #pragma unroll
        for (int mi = 0; mi < 4; ++mi) {
            afh[mi] = *reinterpret_cast<const sh8*>(&AhL[mi * 512 + lane * 8]);
            afl[mi] = *reinterpret_cast<const sh8*>(&AlL[mi * 512 + lane * 8]);
        }
        #pragma unroll
        for (int nj = 0; nj < 4; ++nj) {
            bfh[nj] = *reinterpret_cast<const sh8*>(&BhL[(wv * 4 + nj) * 512 + lane * 8]);
            bfl[nj] = *reinterpret_cast<const sh8*>(&BlL[(wv * 4 + nj) * 512 + lane * 8]);
        }
        #pragma unroll
        for (int mi = 0; mi < 4; ++mi) {
            #pragma unroll
            for (int nj = 0; nj < 4; ++nj) {
                acc[mi][nj] = __builtin_amdgcn_mfma_f32_16x16x32_bf16(afh[mi], bfh[nj], acc[mi][nj], 0, 0, 0);
                acc[mi][nj] = __builtin_amdgcn_mfma_f32_16x16x32_bf16(afh[mi], bfl[nj], acc[mi][nj], 0, 0, 0);
                acc[mi][nj] = __builtin_amdgcn_mfma_f32_16x16x32_bf16(afl[mi], bfh[nj], acc[mi][nj], 0, 0, 0);
            }
        }
    }

    #pragma unroll
    for (int mi = 0; mi < 4; ++mi) {
        #pragma unroll
        for (int q = 0; q < 4; ++q) {
            int grow = m0 + mi * 16 + (lane >> 4) * 4 + q;
            if (grow < M) {
                float dm = (MODE == 0) ? dinv[grow] : 0.f;
                #pragma unroll
                for (int nj = 0; nj < 4; ++nj) {
                    int gcol = wv * 64 + nj * 16 + (lane & 15);
                    float v = acc[mi][nj][q];
                    if (MODE == 0) {
                        Yb[(size_t)grow * 256 + gcol] = bf16rne(v * dm);
                    } else {
                        C[(size_t)grow * 256 + gcol] = fmaxf(v + bias[gcol], 0.f);
                    }
                }
            }
        }
    }
}

// ---------------- aggregation ----------------

// layer-1: z[n] = dinv[n] * ( dinv[n]*x[n] + sum dinv[s]*xb[s] )
// Half-wave dual-edge: 32 lanes x 8B cover a 256B bf16 row; halves do
// alternating edges, combined via shfl_xor(32) at the end.
__global__ __launch_bounds__(256)
void k_agg_x(const float* __restrict__ x, const unsigned short* __restrict__ xb,
             const int* __restrict__ row_start, const int* __restrict__ col,
             const float* __restrict__ dinv, float* __restrict__ z) {
    int wv = threadIdx.x >> 6, lane = threadIdx.x & 63;
    int half = lane >> 5, sub = lane & 31;
    int n = blockIdx.x * 4 + wv;
    bool valid = (n < N_NODES);

    float a0 = 0.f, a1 = 0.f, a2 = 0.f, a3 = 0.f;
    float dn = 0.f;
    if (valid) {
        dn = dinv[n];
        if (half == 0) {
            float4 xs = ((const float4*)x)[(size_t)n * 32 + sub];
            a0 = xs.x * dn; a1 = xs.y * dn; a2 = xs.z * dn; a3 = xs.w * dn;
        }
        const us4* xb4 = (const us4*)xb;
        int e1 = row_start[n + 1];
        for (int e = row_start[n] + half; e < e1; e += 2) {
            int s = col[e];
            float ds = dinv[s];
            us4 v = xb4[(size_t)s * 32 + sub];
            a0 += bf2f(v.x) * ds; a1 += bf2f(v.y) * ds;
            a2 += bf2f(v.z) * ds; a3 += bf2f(v.w) * ds;
        }
    }
    a0 += __shfl_xor(a0, 32, 64);
    a1 += __shfl_xor(a1, 32, 64);
    a2 += __shfl_xor(a2, 32, 64);
    a3 += __shfl_xor(a3, 32, 64);
    if (valid && half == 0) {
        float4 o;
        o.x = a0 * dn; o.y = a1 * dn; o.z = a2 * dn; o.w = a3 * dn;
        ((float4*)z)[(size_t)n * 32 + sub] = o;
    }
}

// layer-2 + relu + mean-pool fused. yb pre-scaled by dinv[src] (bf16).
// row[n] = relu(dinv[n]*(yb[n] + sum yb[col]) + b); sums[batch[n]] += row.
// Half-wave dual-edge: 32 lanes x 16B cover a 512B row. 8 nodes per block,
// LDS-accumulated flush when the block is graph-uniform.
__global__ __launch_bounds__(512)
void k_agg_pool(const unsigned short* __restrict__ yb, const int* __restrict__ row_start,
                const int* __restrict__ col, const float* __restrict__ dinv,
                const float* __restrict__ bias, const int* __restrict__ batch,
                float* __restrict__ sums) {
    __shared__ float lsum[256];
    const int tid = threadIdx.x;
    const int wv = tid >> 6, lane = tid & 63;
    const int half = lane >> 5, sub = lane & 31;
    const int n = blockIdx.x * 8 + wv;
    const bool valid = (n < N_NODES);

    int nlast = min(blockIdx.x * 8 + 7, N_NODES - 1);
    bool uni = (batch[blockIdx.x * 8] == batch[nlast]);

    if (tid < 256) lsum[tid] = 0.f;
    __syncthreads();

    float a[8] = {0.f, 0.f, 0.f, 0.f, 0.f, 0.f, 0.f, 0.f};
    if (valid) {
        const us8* y8 = (const us8*)yb;
        if (half == 0) {
            us8 sv = y8[(size_t)n * 32 + sub];
            #pragma unroll
            for (int j = 0; j < 8; ++j) a[j] = bf2f(sv[j]);
        }
        int e1 = row_start[n + 1];
        for (int e = row_start[n] + half; e < e1; e += 2) {
            int s = col[e];
            us8 v = y8[(size_t)s * 32 + sub];
            #pragma unroll
            for (int j = 0; j < 8; ++j) a[j] += bf2f(v[j]);
        }
    }
    #pragma unroll
    for (int j = 0; j < 8; ++j) a[j] += __shfl_xor(a[j], 32, 64);

    if (valid && half == 0) {
        float dn = dinv[n];
        float4 b0 = ((const float4*)bias)[sub * 2];
        float4 b1 = ((const float4*)bias)[sub * 2 + 1];
        float o[8];
        o[0] = fmaxf(a[0] * dn + b0.x, 0.f);
        o[1] = fmaxf(a[1] * dn + b0.y, 0.f);
        o[2] = fmaxf(a[2] * dn + b0.z, 0.f);
        o[3] = fmaxf(a[3] * dn + b0.w, 0.f);
        o[4] = fmaxf(a[4] * dn + b1.x, 0.f);
        o[5] = fmaxf(a[5] * dn + b1.y, 0.f);
        o[6] = fmaxf(a[6] * dn + b1.z, 0.f);
        o[7] = fmaxf(a[7] * dn + b1.w, 0.f);
        if (uni) {
            #pragma unroll
            for (int j = 0; j < 8; ++j) atomicAdd(&lsum[sub * 8 + j], o[j]);
        } else {
            int g = batch[n];
            #pragma unroll
            for (int j = 0; j < 8; ++j) atomicAdd(&sums[g * 256 + sub * 8 + j], o[j]);
        }
    }
    __syncthreads();
    if (uni && tid < 256) {
        float v = lsum[tid];
        if (v != 0.f) atomicAdd(&sums[batch[blockIdx.x * 8] * 256 + tid], v);
    }
}

// ---------------- pooling bounds + FC ----------------

__global__ void k_bounds(const int* __restrict__ batch, int* __restrict__ bounds) {
    int g = blockIdx.x * blockDim.x + threadIdx.x;
    if (g > N_GRAPHS) return;
    int lo = 0, hi = N_NODES;
    while (lo < hi) {
        int mid = (lo + hi) >> 1;
        if (batch[mid] < g) lo = mid + 1; else hi = mid;
    }
    bounds[g] = lo;
}

__global__ void k_sums_init(float* __restrict__ sums) {
    int i = blockIdx.x * blockDim.x + threadIdx.x;
    if (i < N_GRAPHS * HID_DIM) sums[i] = 0.0f;
}

__global__ void k_final(const float* __restrict__ sums, const int* __restrict__ bounds,
                        const float* __restrict__ Wfc, const float* __restrict__ bfc,
                        float* __restrict__ out) {
    __shared__ float red[HID_DIM];
    int g = blockIdx.x;
    int c = threadIdx.x;
    float cnt = (float)(bounds[g + 1] - bounds[g]);
    float v = sums[g * HID_DIM + c] / fmaxf(cnt, 1.0f) * Wfc[c];
    red[c] = v;
    __syncthreads();
    for (int s = HID_DIM / 2; s > 0; s >>= 1) {
        if (c < s) red[c] += red[c + s];
        __syncthreads();
    }
    if (c == 0) out[g] = red[0] + bfc[0];
}

// ---------------- launch ----------------

extern "C" void kernel_launch(void* const* d_in, const int* in_sizes, int n_in,
                              void* d_out, int out_size, void* d_ws, size_t ws_size,
                              hipStream_t stream) {
    const float* x    = (const float*)d_in[0];
    const int*   ei   = (const int*)d_in[1];
    const int*   batch= (const int*)d_in[2];
    const float* W1   = (const float*)d_in[3];
    const float* b1   = (const float*)d_in[4];
    const float* W2   = (const float*)d_in[5];
    const float* b2   = (const float*)d_in[6];
    const float* Wfc  = (const float*)d_in[7];
    const float* bfc  = (const float*)d_in[8];
    float* out = (float*)d_out;

    const int* src = ei;
    const int* dst = ei + N_EDGES;

    char* ws = (char*)d_ws;
    const size_t BUF_BYTES = (size_t)N_NODES * HID_DIM * sizeof(float);  // 51.2 MB
    size_t off = 0;
    float* region0   = (float*)(ws + off); off += BUF_BYTES;   // h1
    char*  region1   = (char*) (ws + off); off += BUF_BYTES;   // z/y2b front, xb back
    int*   deg_i     = (int*)  (ws + off); off += 200704;
    int*   cursor    = (int*)  (ws + off); off += 200704;
    float* dinv      = (float*)(ws + off); off += 200704;
    int*   row_start = (int*)  (ws + off); off += 200704;
    int*   col       = (int*)  (ws + off); off += (size_t)N_EDGES * 4;
    unsigned short* Bh1 = (unsigned short*)(ws + off); off += 65536;
    unsigned short* Bl1 = (unsigned short*)(ws + off); off += 65536;
    unsigned short* Bh2 = (unsigned short*)(ws + off); off += 131072;
    unsigned short* Bl2 = (unsigned short*)(ws + off); off += 131072;
    float* sums      = (float*)(ws + off); off += 65536;
    int*   bounds    = (int*)  (ws + off); off += 512;
    (void)ws_size; (void)in_sizes; (void)n_in; (void)out_size;

    // region1 overlays (lifetimes disjoint):
    //   z   [N,128] fp32 : front — written by agg_x, read by GEMM1, then dead
    //   y2b [N,256] bf16 : front — written by GEMM2, read by agg_pool
    //   xb  [N,128] bf16 : back  — written by x2bf, read by agg_x, then dead
    float*          z   = (float*)region1;
    unsigned short* y2b = (unsigned short*)region1;
    unsigned short* xb  = (unsigned short*)(region1 + (size_t)N_NODES * IN_DIM * sizeof(float));
    float* h1 = region0;

    // 1. CSR build + dinv + weight split + x->bf16
    hipMemsetAsync(deg_i, 0, 2 * 200704, stream);
    k_deg_count<<<(N_EDGES + 255) / 256, 256, 0, stream>>>(dst, deg_i);
    k_dinv<<<(N_NODES + 255) / 256, 256, 0, stream>>>(deg_i, dinv);
    k_scan<<<1, SCAN_THREADS, 0, stream>>>(deg_i, row_start);
    k_csr_fill<<<(N_EDGES + 255) / 256, 256, 0, stream>>>(src, dst, row_start, cursor, col);
    k_x2bf<<<(N_NODES * IN_DIM / 4 + 255) / 256, 256, 0, stream>>>(x, xb);
    k_wsplit<<<(IN_DIM * 256 + 255) / 256, 256, 0, stream>>>(W1, Bh1, Bl1, IN_DIM);
    k_wsplit<<<(HID_DIM * 256 + 255) / 256, 256, 0, stream>>>(W2, Bh2, Bl2, HID_DIM);
    k_bounds<<<1, 128, 0, stream>>>(batch, bounds);
    k_sums_init<<<(N_GRAPHS * HID_DIM + 255) / 256, 256, 0, stream>>>(sums);

    const int gemm_grid = (N_NODES + 63) / 64;  // 782

    // 2. layer 1: z = A_hat @ x ; h1 = relu(z @ W1 + b1)
    k_agg_x<<<(N_NODES + 3) / 4, 256, 0, stream>>>(x, xb, row_start, col, dinv, z);
    k_gemm_mfma<1><<<gemm_grid, 256, 0, stream>>>(z, Bh1, Bl1, dinv, b1, h1, nullptr, N_NODES, IN_DIM);

    // 3. layer 2: y2b = bf16((h1 @ W2) * dinv) ; fused agg+relu+pool
    k_gemm_mfma<0><<<gemm_grid, 256, 0, stream>>>(h1, Bh2, Bl2, dinv, b2, nullptr, y2b, N_NODES, HID_DIM);
    k_agg_pool<<<(N_NODES + 7) / 8, 512, 0, stream>>>(y2b, row_start, col, dinv, b2, batch, sums);

    // 4. fc
    k_final<<<N_GRAPHS, HID_DIM, 0, stream>>>(sums, bounds, Wfc, bfc, out);
}